// Round 1
// baseline (735.257 us; speedup 1.0000x reference)
//
#include <hip/hip_runtime.h>

#define NT 8192       // tokens
#define NJ 24         // joints
#define DD 256        // per-joint dim
#define NH 8          // heads
#define FF 32         // head dim
#define C3 768        // q(256) + k(256) + v(256)

typedef __attribute__((ext_vector_type(8))) short bf16x8;
typedef __attribute__((ext_vector_type(4))) float f32x4;

__device__ __forceinline__ unsigned short f2bf(float f) {
    union { float f; unsigned int u; } c; c.f = f;
    unsigned int u = c.u;
    unsigned int r = (u + 0x7fffu + ((u >> 16) & 1u)) >> 16;
    return (unsigned short)r;
}
__device__ __forceinline__ float bf2f(unsigned short h) {
    union { unsigned int u; float f; } c; c.u = ((unsigned int)h) << 16;
    return c.f;
}

// ---------------- pack kernels ----------------
// WbT[n][c][d] bf16: c<256 -> Wq[h][n][d][f]; 256..511 -> Wk[h][d][f]; 512.. -> Wv
__global__ void pack_w(const float* __restrict__ Wq, const float* __restrict__ Wk,
                       const float* __restrict__ Wv, unsigned short* __restrict__ wbt) {
    size_t idx = (size_t)blockIdx.x * 256 + threadIdx.x;
    const size_t total = (size_t)NJ * C3 * DD;
    if (idx >= total) return;
    int d = idx & 255;
    int rest = (int)(idx >> 8);
    int c = rest % C3;
    int n = rest / C3;
    float v;
    if (c < 256) {
        int h = c >> 5, f = c & 31;
        v = Wq[((((size_t)h * NJ + n) * DD) + d) * FF + f];
    } else if (c < 512) {
        int cc = c - 256; int h = cc >> 5, f = cc & 31;
        v = Wk[(((size_t)h * DD) + d) * FF + f];
    } else {
        int cc = c - 512; int h = cc >> 5, f = cc & 31;
        v = Wv[(((size_t)h * DD) + d) * FF + f];
    }
    wbt[idx] = f2bf(v);
}

__global__ void pack_b(const float* __restrict__ bq, const float* __restrict__ bk,
                       const float* __restrict__ bv, float* __restrict__ bias) {
    int idx = blockIdx.x * 256 + threadIdx.x;   // NJ*C3 = 18432
    if (idx >= NJ * C3) return;
    int c = idx % C3;
    int n = idx / C3;
    float v;
    if (c < 256) {
        int h = c >> 5, f = c & 31;
        v = bq[((h * NJ + n) * FF) + f];
    } else if (c < 512) {
        int cc = c - 256; int h = cc >> 5, f = cc & 31;
        v = bk[h * FF + f];
    } else {
        int cc = c - 512; int h = cc >> 5, f = cc & 31;
        v = bv[h * FF + f];
    }
    bias[idx] = v;
}

// ---------------- QKV projection GEMM ----------------
// per joint n: C(8192x768) = A(8192x256) @ B(256x768), bf16 MFMA, 128x128 tile
#define BM 128
#define BN 128
#define LDSP 72   // padded LDS row stride in bf16 (64 + 8)

__global__ __launch_bounds__(256, 2)
void gemm_qkv(const float* __restrict__ x, const unsigned short* __restrict__ wbt,
              const float* __restrict__ bias, unsigned short* __restrict__ qkv,
              int t0) {
    const int nb = blockIdx.x;   // 0..5   col block
    const int mb = blockIdx.y;   // row (token) block within chunk
    const int nj = blockIdx.z;   // joint
    const int tid = threadIdx.x;
    const int wave = tid >> 6, lane = tid & 63;

    __shared__ unsigned short As[BM * LDSP];
    __shared__ unsigned short Bs[BN * LDSP];

    f32x4 acc[4][4];
    #pragma unroll
    for (int i = 0; i < 4; ++i)
        #pragma unroll
        for (int j = 0; j < 4; ++j)
            #pragma unroll
            for (int r = 0; r < 4; ++r) acc[i][j][r] = 0.f;

    const int trow0 = t0 + mb * BM;
    const float* xA = x + (size_t)trow0 * (NJ * DD) + nj * DD;
    const unsigned short* wB = wbt + ((size_t)nj * C3 + (size_t)nb * BN) * DD;

    for (int kb = 0; kb < 4; ++kb) {
        // stage A: 128 tokens x 64 d, fp32 -> bf16
        {
            const float* src = xA + kb * 64;
            #pragma unroll
            for (int j = 0; j < 8; ++j) {
                int q = tid + j * 256;        // 0..2047
                int row = q >> 4;             // 16 float4 per row
                int c4 = (q & 15) * 4;
                float4 v = *(const float4*)(src + (size_t)row * (NJ * DD) + c4);
                ushort4 h;
                h.x = f2bf(v.x); h.y = f2bf(v.y); h.z = f2bf(v.z); h.w = f2bf(v.w);
                *(ushort4*)&As[row * LDSP + c4] = h;
            }
        }
        // stage B: 128 cols(c) x 64 d, already bf16 & pre-transposed
        {
            const unsigned short* src = wB + kb * 64;
            #pragma unroll
            for (int j = 0; j < 4; ++j) {
                int q = tid + j * 256;        // 0..1023
                int row = q >> 3;             // 8 x 16B chunks per row
                int c8 = (q & 7) * 8;
                int4 v = *(const int4*)(src + (size_t)row * DD + c8);
                *(int4*)&Bs[row * LDSP + c8] = v;
            }
        }
        __syncthreads();
        const int wr = (wave >> 1) * 64;
        const int wc = (wave & 1) * 64;
        const int lr = lane & 15;
        const int kq = (lane >> 4) * 8;
        #pragma unroll
        for (int kk = 0; kk < 2; ++kk) {
            bf16x8 a[4], b[4];
            #pragma unroll
            for (int i = 0; i < 4; ++i)
                a[i] = *(const bf16x8*)&As[(wr + i * 16 + lr) * LDSP + kk * 32 + kq];
            #pragma unroll
            for (int j = 0; j < 4; ++j)
                b[j] = *(const bf16x8*)&Bs[(wc + j * 16 + lr) * LDSP + kk * 32 + kq];
            #pragma unroll
            for (int i = 0; i < 4; ++i)
                #pragma unroll
                for (int j = 0; j < 4; ++j)
                    acc[i][j] = __builtin_amdgcn_mfma_f32_16x16x32_bf16(a[i], b[j], acc[i][j], 0, 0, 0);
        }
        __syncthreads();
    }

    // epilogue: C/D layout col=lane&15, row=(lane>>4)*4+reg
    const int wr = (wave >> 1) * 64;
    const int wc = (wave & 1) * 64;
    const int ln = lane & 15;
    const int lq = (lane >> 4) * 4;
    float bv[4];
    #pragma unroll
    for (int j = 0; j < 4; ++j)
        bv[j] = bias[nj * C3 + nb * BN + wc + j * 16 + ln];
    #pragma unroll
    for (int i = 0; i < 4; ++i) {
        #pragma unroll
        for (int r = 0; r < 4; ++r) {
            int trow = mb * BM + wr + i * 16 + lq + r;   // local within chunk
            size_t base = ((size_t)trow * NJ + nj) * C3 + (size_t)nb * BN;
            #pragma unroll
            for (int j = 0; j < 4; ++j) {
                float val = acc[i][j][r] + bv[j];
                qkv[base + wc + j * 16 + ln] = f2bf(val);
            }
        }
    }
}

// ---------------- attention + residual + LayerNorm ----------------
__global__ __launch_bounds__(256, 2)
void attn_ln(const unsigned short* __restrict__ qkv, const float* __restrict__ x,
             const float* __restrict__ gamma, const float* __restrict__ beta,
             float* __restrict__ out, int t0) {
    const int tloc = blockIdx.x;
    const int t = t0 + tloc;
    const int tid = threadIdx.x;
    const int wave = tid >> 6, lane = tid & 63;

    __shared__ unsigned short qs[NJ * C3];   // 36864 B
    __shared__ float os[NJ * DD];            // 24576 B
    __shared__ float red[8];
    __shared__ float stats[2];

    // load qkv for this token (2304 int4)
    {
        const int4* src = (const int4*)(qkv + (size_t)tloc * NJ * C3);
        int4* dst = (int4*)qs;
        #pragma unroll
        for (int j = 0; j < 9; ++j)
            dst[tid + j * 256] = src[tid + j * 256];
    }
    __syncthreads();

    if (tid < NH * NJ) {
        const int h = tid / NJ;
        const int n = tid - h * NJ;
        const int hb = h * FF;
        float qf[FF];
        #pragma unroll
        for (int f = 0; f < FF; ++f) qf[f] = bf2f(qs[n * C3 + hb + f]);
        float s[NJ];
        float mx = -1e30f;
        for (int m = 0; m < NJ; ++m) {
            const unsigned short* kp = &qs[m * C3 + 256 + hb];
            float a = 0.f;
            #pragma unroll
            for (int f = 0; f < FF; ++f) a += qf[f] * bf2f(kp[f]);
            a *= 0.17677669529663687f;   // 1/sqrt(32)
            s[m] = a;
            mx = fmaxf(mx, a);
        }
        float sum = 0.f;
        for (int m = 0; m < NJ; ++m) { s[m] = __expf(s[m] - mx); sum += s[m]; }
        float inv = 1.f / sum;
        float o[FF];
        #pragma unroll
        for (int f = 0; f < FF; ++f) o[f] = 0.f;
        for (int m = 0; m < NJ; ++m) {
            float w = s[m] * inv;
            const unsigned short* vp = &qs[m * C3 + 512 + hb];
            #pragma unroll
            for (int f = 0; f < FF; ++f) o[f] += w * bf2f(vp[f]);
        }
        #pragma unroll
        for (int f = 0; f < FF; ++f) os[n * DD + hb + f] = o[f];
    }
    __syncthreads();

    // residual + LayerNorm over 6144, fp32 x (exact residual path)
    const float4* x4 = (const float4*)(x + (size_t)t * (NJ * DD));
    const float4* o4 = (const float4*)os;
    float4 yv[6];
    float sum = 0.f, sq = 0.f;
    #pragma unroll
    for (int j = 0; j < 6; ++j) {
        float4 a = x4[tid + j * 256];
        float4 b = o4[tid + j * 256];
        float4 y;
        y.x = a.x + b.x; y.y = a.y + b.y; y.z = a.z + b.z; y.w = a.w + b.w;
        yv[j] = y;
        sum += y.x + y.y + y.z + y.w;
        sq  += y.x * y.x + y.y * y.y + y.z * y.z + y.w * y.w;
    }
    #pragma unroll
    for (int off = 32; off > 0; off >>= 1) {
        sum += __shfl_down(sum, off);
        sq  += __shfl_down(sq, off);
    }
    if (lane == 0) { red[wave] = sum; red[4 + wave] = sq; }
    __syncthreads();
    if (tid == 0) {
        float s = red[0] + red[1] + red[2] + red[3];
        float q = red[4] + red[5] + red[6] + red[7];
        float mu = s * (1.f / 6144.f);
        float var = q * (1.f / 6144.f) - mu * mu;
        stats[0] = mu;
        stats[1] = rsqrtf(var + 1e-5f);
    }
    __syncthreads();
    const float mu = stats[0], rs = stats[1];
    const float4* g4 = (const float4*)gamma;
    const float4* b4 = (const float4*)beta;
    float4* out4 = (float4*)(out + (size_t)t * (NJ * DD));
    #pragma unroll
    for (int j = 0; j < 6; ++j) {
        float4 g = g4[tid + j * 256];
        float4 bb = b4[tid + j * 256];
        float4 y = yv[j];
        y.x = (y.x - mu) * rs * g.x + bb.x;
        y.y = (y.y - mu) * rs * g.y + bb.y;
        y.z = (y.z - mu) * rs * g.z + bb.z;
        y.w = (y.w - mu) * rs * g.w + bb.w;
        out4[tid + j * 256] = y;
    }
}

// ---------------- launch ----------------
extern "C" void kernel_launch(void* const* d_in, const int* in_sizes, int n_in,
                              void* d_out, int out_size, void* d_ws, size_t ws_size,
                              hipStream_t stream) {
    const float* x     = (const float*)d_in[0];
    const float* Wq    = (const float*)d_in[1];
    const float* bq    = (const float*)d_in[2];
    const float* Wk    = (const float*)d_in[3];
    const float* bk    = (const float*)d_in[4];
    const float* Wv    = (const float*)d_in[5];
    const float* bv    = (const float*)d_in[6];
    const float* gamma = (const float*)d_in[7];
    const float* beta  = (const float*)d_in[8];
    float* out = (float*)d_out;

    char* ws = (char*)d_ws;
    const size_t wbt_bytes  = (size_t)NJ * C3 * DD * 2;  // 9,437,184
    const size_t bias_bytes = (size_t)NJ * C3 * 4;       // 73,728
    unsigned short* wbt = (unsigned short*)ws;
    float* bias = (float*)(ws + wbt_bytes);
    unsigned short* qkv = (unsigned short*)(ws + wbt_bytes + bias_bytes);

    // chunk tokens so qkv scratch fits in ws
    size_t avail = (ws_size > wbt_bytes + bias_bytes) ? ws_size - wbt_bytes - bias_bytes : 0;
    int chunk = NT;
    while (chunk > 128 && (size_t)chunk * NJ * C3 * 2 > avail) chunk >>= 1;

    const size_t wtotal = (size_t)NJ * C3 * DD;
    pack_w<<<dim3((unsigned)((wtotal + 255) / 256)), dim3(256), 0, stream>>>(Wq, Wk, Wv, wbt);
    pack_b<<<dim3((NJ * C3 + 255) / 256), dim3(256), 0, stream>>>(bq, bk, bv, bias);

    for (int t0 = 0; t0 < NT; t0 += chunk) {
        gemm_qkv<<<dim3(6, chunk / BM, NJ), dim3(256), 0, stream>>>(x, wbt, bias, qkv, t0);
        attn_ln<<<dim3(chunk), dim3(256), 0, stream>>>(qkv, x, gamma, beta, out, t0);
    }
}

// Round 2
// 678.459 us; speedup vs baseline: 1.0837x; 1.0837x over previous
//
#include <hip/hip_runtime.h>

#define NT 8192       // tokens
#define NJ 24         // joints
#define DD 256        // per-joint dim
#define NH 8          // heads
#define FF 32         // head dim
#define C3 768        // q(256) + k(256) + v(256)

typedef __attribute__((ext_vector_type(8))) short bf16x8;
typedef __attribute__((ext_vector_type(4))) float f32x4;

__device__ __forceinline__ unsigned short f2bf(float f) {
    union { float f; unsigned int u; } c; c.f = f;
    unsigned int u = c.u;
    unsigned int r = (u + 0x7fffu + ((u >> 16) & 1u)) >> 16;
    return (unsigned short)r;
}
__device__ __forceinline__ float bf2f(unsigned short h) {
    union { unsigned int u; float f; } c; c.u = ((unsigned int)h) << 16;
    return c.f;
}
__device__ __forceinline__ float u2f(unsigned int u) {
    union { unsigned int u; float f; } c; c.u = u;
    return c.f;
}
// unpack 8 bf16 (one uint4) -> 8 floats. elem0 = low ushort of .x
__device__ __forceinline__ void up8(uint4 w, float* f) {
    f[0] = u2f(w.x << 16); f[1] = u2f(w.x & 0xffff0000u);
    f[2] = u2f(w.y << 16); f[3] = u2f(w.y & 0xffff0000u);
    f[4] = u2f(w.z << 16); f[5] = u2f(w.z & 0xffff0000u);
    f[6] = u2f(w.w << 16); f[7] = u2f(w.w & 0xffff0000u);
}

// ---------------- pack kernels ----------------
__global__ void pack_w(const float* __restrict__ Wq, const float* __restrict__ Wk,
                       const float* __restrict__ Wv, unsigned short* __restrict__ wbt) {
    size_t idx = (size_t)blockIdx.x * 256 + threadIdx.x;
    const size_t total = (size_t)NJ * C3 * DD;
    if (idx >= total) return;
    int d = idx & 255;
    int rest = (int)(idx >> 8);
    int c = rest % C3;
    int n = rest / C3;
    float v;
    if (c < 256) {
        int h = c >> 5, f = c & 31;
        v = Wq[((((size_t)h * NJ + n) * DD) + d) * FF + f];
    } else if (c < 512) {
        int cc = c - 256; int h = cc >> 5, f = cc & 31;
        v = Wk[(((size_t)h * DD) + d) * FF + f];
    } else {
        int cc = c - 512; int h = cc >> 5, f = cc & 31;
        v = Wv[(((size_t)h * DD) + d) * FF + f];
    }
    wbt[idx] = f2bf(v);
}

__global__ void pack_b(const float* __restrict__ bq, const float* __restrict__ bk,
                       const float* __restrict__ bv, float* __restrict__ bias) {
    int idx = blockIdx.x * 256 + threadIdx.x;   // NJ*C3 = 18432
    if (idx >= NJ * C3) return;
    int c = idx % C3;
    int n = idx / C3;
    float v;
    if (c < 256) {
        int h = c >> 5, f = c & 31;
        v = bq[((h * NJ + n) * FF) + f];
    } else if (c < 512) {
        int cc = c - 256; int h = cc >> 5, f = cc & 31;
        v = bk[h * FF + f];
    } else {
        int cc = c - 512; int h = cc >> 5, f = cc & 31;
        v = bv[h * FF + f];
    }
    bias[idx] = v;
}

// x fp32 -> bf16 (xb), one pass
__global__ void pack_x(const float* __restrict__ x, unsigned short* __restrict__ xb) {
    size_t idx = (size_t)blockIdx.x * 256 + threadIdx.x;   // one float4 each
    const size_t total = (size_t)NT * NJ * DD / 4;
    if (idx >= total) return;
    float4 v = ((const float4*)x)[idx];
    ushort4 h;
    h.x = f2bf(v.x); h.y = f2bf(v.y); h.z = f2bf(v.z); h.w = f2bf(v.w);
    ((ushort4*)xb)[idx] = h;
}

// ---------------- QKV projection GEMM ----------------
// per joint n: C(chunk x 768) = A(chunk x 256) @ B(256 x 768), bf16 MFMA, 128x128 tile
#define BM 128
#define BN 128
#define LDSP 72   // padded LDS row stride in bf16 (64 + 8): stride 144 B -> 2-way (free)

__global__ __launch_bounds__(256, 2)
void gemm_qkv(const unsigned short* __restrict__ xb, const unsigned short* __restrict__ wbt,
              const float* __restrict__ bias, unsigned short* __restrict__ qkv,
              int t0) {
    const int nb = blockIdx.x;   // 0..5   col block
    const int mb = blockIdx.y;   // row (token) block within chunk
    const int nj = blockIdx.z;   // joint
    const int tid = threadIdx.x;
    const int wave = tid >> 6, lane = tid & 63;

    __shared__ unsigned short As[BM * LDSP];
    __shared__ unsigned short Bs[BN * LDSP];

    f32x4 acc[4][4];
    #pragma unroll
    for (int i = 0; i < 4; ++i)
        #pragma unroll
        for (int j = 0; j < 4; ++j)
            #pragma unroll
            for (int r = 0; r < 4; ++r) acc[i][j][r] = 0.f;

    const int trow0 = t0 + mb * BM;
    const unsigned short* xA = xb + (size_t)trow0 * (NJ * DD) + nj * DD;
    const unsigned short* wB = wbt + ((size_t)nj * C3 + (size_t)nb * BN) * DD;

    for (int kb = 0; kb < 4; ++kb) {
        // stage A: 128 tokens x 64 d, bf16, 16B chunks
        {
            const unsigned short* src = xA + kb * 64;
            #pragma unroll
            for (int j = 0; j < 4; ++j) {
                int q = tid + j * 256;        // 0..1023
                int row = q >> 3;             // 8 x 16B chunks per row
                int c8 = (q & 7) * 8;
                int4 v = *(const int4*)(src + (size_t)row * (NJ * DD) + c8);
                *(int4*)&As[row * LDSP + c8] = v;
            }
        }
        // stage B: 128 cols(c) x 64 d, bf16 pre-transposed
        {
            const unsigned short* src = wB + kb * 64;
            #pragma unroll
            for (int j = 0; j < 4; ++j) {
                int q = tid + j * 256;        // 0..1023
                int row = q >> 3;
                int c8 = (q & 7) * 8;
                int4 v = *(const int4*)(src + (size_t)row * DD + c8);
                *(int4*)&Bs[row * LDSP + c8] = v;
            }
        }
        __syncthreads();
        const int wr = (wave >> 1) * 64;
        const int wc = (wave & 1) * 64;
        const int lr = lane & 15;
        const int kq = (lane >> 4) * 8;
        #pragma unroll
        for (int kk = 0; kk < 2; ++kk) {
            bf16x8 a[4], b[4];
            #pragma unroll
            for (int i = 0; i < 4; ++i)
                a[i] = *(const bf16x8*)&As[(wr + i * 16 + lr) * LDSP + kk * 32 + kq];
            #pragma unroll
            for (int j = 0; j < 4; ++j)
                b[j] = *(const bf16x8*)&Bs[(wc + j * 16 + lr) * LDSP + kk * 32 + kq];
            #pragma unroll
            for (int i = 0; i < 4; ++i)
                #pragma unroll
                for (int j = 0; j < 4; ++j)
                    acc[i][j] = __builtin_amdgcn_mfma_f32_16x16x32_bf16(a[i], b[j], acc[i][j], 0, 0, 0);
        }
        __syncthreads();
    }

    // epilogue: C/D layout col=lane&15, row=(lane>>4)*4+reg
    const int wr = (wave >> 1) * 64;
    const int wc = (wave & 1) * 64;
    const int ln = lane & 15;
    const int lq = (lane >> 4) * 4;
    float bv[4];
    #pragma unroll
    for (int j = 0; j < 4; ++j)
        bv[j] = bias[nj * C3 + nb * BN + wc + j * 16 + ln];
    #pragma unroll
    for (int i = 0; i < 4; ++i) {
        #pragma unroll
        for (int r = 0; r < 4; ++r) {
            int trow = mb * BM + wr + i * 16 + lq + r;   // local within chunk
            size_t base = ((size_t)trow * NJ + nj) * C3 + (size_t)nb * BN;
            #pragma unroll
            for (int j = 0; j < 4; ++j) {
                float val = acc[i][j][r] + bv[j];
                qkv[base + wc + j * 16 + ln] = f2bf(val);
            }
        }
    }
}

// ---------------- attention + residual + LayerNorm ----------------
__global__ __launch_bounds__(256, 4)
void attn_ln(const unsigned short* __restrict__ qkv, const float* __restrict__ x,
             const float* __restrict__ gamma, const float* __restrict__ beta,
             float* __restrict__ out, int t0) {
    const int tloc = blockIdx.x;
    const int t = t0 + tloc;
    const int tid = threadIdx.x;
    const int wave = tid >> 6, lane = tid & 63;

    // qkv staged as bf16 (36864 B); after attention the SAME region is reused
    // as the fp32 attention-output buffer (24576 B) -> 37 KB LDS, 4 blocks/CU
    __shared__ __align__(16) char smem[NJ * C3 * 2];
    unsigned short* qs = (unsigned short*)smem;
    float* os = (float*)smem;
    __shared__ float red[8];
    __shared__ float stats[2];

    // load qkv for this token (2304 int4)
    {
        const int4* src = (const int4*)(qkv + (size_t)tloc * NJ * C3);
        int4* dst = (int4*)qs;
        #pragma unroll
        for (int j = 0; j < 9; ++j)
            dst[tid + j * 256] = src[tid + j * 256];
    }
    __syncthreads();

    float o[FF];
    const bool active = tid < NH * NJ;
    int hn = 0, nn = 0;
    if (active) {
        const int h = tid / NJ;
        const int n = tid - h * NJ;
        hn = h; nn = n;
        const int hb = h * FF;   // ushort offset within a joint row
        float qf[FF];
        {
            const uint4* qp = (const uint4*)(qs + n * C3 + hb);
            #pragma unroll
            for (int jj = 0; jj < 4; ++jj) { uint4 w = qp[jj]; up8(w, &qf[jj * 8]); }
        }
        float s[NJ];
        float mx = -1e30f;
        for (int m = 0; m < NJ; ++m) {
            const uint4* kp = (const uint4*)(qs + m * C3 + 256 + hb);
            float a = 0.f;
            #pragma unroll
            for (int jj = 0; jj < 4; ++jj) {
                uint4 w = kp[jj];
                float kf[8]; up8(w, kf);
                #pragma unroll
                for (int e = 0; e < 8; ++e) a += qf[jj * 8 + e] * kf[e];
            }
            a *= 0.17677669529663687f;   // 1/sqrt(32)
            s[m] = a;
            mx = fmaxf(mx, a);
        }
        float sum = 0.f;
        for (int m = 0; m < NJ; ++m) { s[m] = __expf(s[m] - mx); sum += s[m]; }
        float inv = 1.f / sum;
        #pragma unroll
        for (int f = 0; f < FF; ++f) o[f] = 0.f;
        for (int m = 0; m < NJ; ++m) {
            float w = s[m] * inv;
            const uint4* vp = (const uint4*)(qs + m * C3 + 512 + hb);
            #pragma unroll
            for (int jj = 0; jj < 4; ++jj) {
                uint4 wv = vp[jj];
                float vf[8]; up8(wv, vf);
                #pragma unroll
                for (int e = 0; e < 8; ++e) o[jj * 8 + e] += w * vf[e];
            }
        }
    }
    __syncthreads();   // all reads of qs done; safe to overwrite as os
    if (active) {
        float* dst = os + nn * DD + hn * FF;
        #pragma unroll
        for (int jj = 0; jj < 8; ++jj)
            *(float4*)(dst + jj * 4) = make_float4(o[jj * 4], o[jj * 4 + 1], o[jj * 4 + 2], o[jj * 4 + 3]);
    }
    __syncthreads();

    // residual + LayerNorm over 6144, fp32 x (exact residual path)
    const float4* x4 = (const float4*)(x + (size_t)t * (NJ * DD));
    const float4* o4 = (const float4*)os;
    float4 yv[6];
    float sum = 0.f, sq = 0.f;
    #pragma unroll
    for (int j = 0; j < 6; ++j) {
        float4 a = x4[tid + j * 256];
        float4 b = o4[tid + j * 256];
        float4 y;
        y.x = a.x + b.x; y.y = a.y + b.y; y.z = a.z + b.z; y.w = a.w + b.w;
        yv[j] = y;
        sum += y.x + y.y + y.z + y.w;
        sq  += y.x * y.x + y.y * y.y + y.z * y.z + y.w * y.w;
    }
    #pragma unroll
    for (int off = 32; off > 0; off >>= 1) {
        sum += __shfl_down(sum, off);
        sq  += __shfl_down(sq, off);
    }
    if (lane == 0) { red[wave] = sum; red[4 + wave] = sq; }
    __syncthreads();
    if (tid == 0) {
        float s = red[0] + red[1] + red[2] + red[3];
        float q = red[4] + red[5] + red[6] + red[7];
        float mu = s * (1.f / 6144.f);
        float var = q * (1.f / 6144.f) - mu * mu;
        stats[0] = mu;
        stats[1] = rsqrtf(var + 1e-5f);
    }
    __syncthreads();
    const float mu = stats[0], rs = stats[1];
    const float4* g4 = (const float4*)gamma;
    const float4* b4 = (const float4*)beta;
    float4* out4 = (float4*)(out + (size_t)t * (NJ * DD));
    #pragma unroll
    for (int j = 0; j < 6; ++j) {
        float4 g = g4[tid + j * 256];
        float4 bb = b4[tid + j * 256];
        float4 y = yv[j];
        y.x = (y.x - mu) * rs * g.x + bb.x;
        y.y = (y.y - mu) * rs * g.y + bb.y;
        y.z = (y.z - mu) * rs * g.z + bb.z;
        y.w = (y.w - mu) * rs * g.w + bb.w;
        out4[tid + j * 256] = y;
    }
}

// ---------------- launch ----------------
extern "C" void kernel_launch(void* const* d_in, const int* in_sizes, int n_in,
                              void* d_out, int out_size, void* d_ws, size_t ws_size,
                              hipStream_t stream) {
    const float* x     = (const float*)d_in[0];
    const float* Wq    = (const float*)d_in[1];
    const float* bq    = (const float*)d_in[2];
    const float* Wk    = (const float*)d_in[3];
    const float* bk    = (const float*)d_in[4];
    const float* Wv    = (const float*)d_in[5];
    const float* bv    = (const float*)d_in[6];
    const float* gamma = (const float*)d_in[7];
    const float* beta  = (const float*)d_in[8];
    float* out = (float*)d_out;

    char* ws = (char*)d_ws;
    const size_t wbt_bytes  = (size_t)NJ * C3 * DD * 2;        // 9,437,184
    const size_t bias_bytes = (size_t)NJ * C3 * 4;             // 73,728
    const size_t xb_bytes   = (size_t)NT * NJ * DD * 2;        // 100,663,296
    unsigned short* wbt = (unsigned short*)ws;
    float* bias = (float*)(ws + wbt_bytes);
    unsigned short* xb  = (unsigned short*)(ws + wbt_bytes + bias_bytes);
    unsigned short* qkv = (unsigned short*)(ws + wbt_bytes + bias_bytes + xb_bytes);

    // chunk tokens so qkv scratch fits in remaining ws
    const size_t fixed = wbt_bytes + bias_bytes + xb_bytes;
    size_t avail = (ws_size > fixed) ? ws_size - fixed : 0;
    int chunk = NT;
    while (chunk > BM && (size_t)chunk * NJ * C3 * 2 > avail) chunk >>= 1;

    const size_t wtotal = (size_t)NJ * C3 * DD;
    pack_w<<<dim3((unsigned)((wtotal + 255) / 256)), dim3(256), 0, stream>>>(Wq, Wk, Wv, wbt);
    pack_b<<<dim3((NJ * C3 + 255) / 256), dim3(256), 0, stream>>>(bq, bk, bv, bias);
    const size_t xtotal4 = (size_t)NT * NJ * DD / 4;
    pack_x<<<dim3((unsigned)((xtotal4 + 255) / 256)), dim3(256), 0, stream>>>(x, xb);

    for (int t0 = 0; t0 < NT; t0 += chunk) {
        gemm_qkv<<<dim3(6, chunk / BM, NJ), dim3(256), 0, stream>>>(xb, wbt, bias, qkv, t0);
        attn_ln<<<dim3(chunk), dim3(256), 0, stream>>>(qkv, x, gamma, beta, out, t0);
    }
}